// Round 8
// baseline (346.661 us; speedup 1.0000x reference)
//
#include <hip/hip_runtime.h>

#define D_FEAT 256
#define UNITS  128

#define NBITS  7            // coarse bin = 128 dst nodes
#define BINSZ  128
#define BINCAP 2432         // Poisson(2046) + 8.5 sigma — cannot overflow for random dst
#define MAXNB  800          // >= ceil(100000/128) = 782

typedef __attribute__((ext_vector_type(8))) short short8;   // 8 bf16 (4 VGPRs)
typedef __attribute__((ext_vector_type(4))) float floatx4;

__device__ inline ushort f2bf(float f) {          // fp32 -> bf16, round-nearest-even
    uint u = __float_as_uint(f);
    uint r = u + 0x7FFF + ((u >> 16) & 1);
    return (ushort)(r >> 16);
}

// ---------------------------------------------------------------------------
// One-time prep: w -> fragment-major bf16. Fragment i=(s*8+c)*64+lane holds
// the 8 bf16 B-elements lane needs for mfma(s,c):
//   wF[i*8+j] = bf16( w[(s*32+quad*8+j)*128 + (c*16+m16)] ),  lane=quad*16+m16
// 64 KB total; gemm's B ds_reads become lane-linear (conflict-free).
// ---------------------------------------------------------------------------
__global__ __launch_bounds__(256) void wf_prep_kernel(const float* __restrict__ w,
                                                      ushort* __restrict__ wF) {
    int idx = blockIdx.x * 256 + threadIdx.x;     // 0..32767
    int j    = idx & 7;
    int i    = idx >> 3;
    int lane = i & 63;
    int c    = (i >> 6) & 7;
    int s    = i >> 9;
    int m16  = lane & 15;
    int quad = lane >> 4;
    int k = s * 32 + quad * 8 + j;
    int n = c * 16 + m16;
    wF[idx] = f2bf(w[(size_t)k * UNITS + n]);
}

// ---------------------------------------------------------------------------
// h_bf16[M][128] = bf16( x[M][256] @ w ) via mfma_f32_16x16x32_bf16.
// Pipelined multi-tile loop (round-7 post-mortem: one-shot code serialized the
// A-loads at VGPR=52). Per iter: convert(prev loads) -> issue next-tile loads
// (in flight across MFMAs+stores) -> 64 MFMA -> store. B from LDS, staged once
// per block in fragment-major order: ds_read_b128 at lane*16, conflict-free.
// ---------------------------------------------------------------------------
__global__ __launch_bounds__(256, 2) void gemm_mfma3_kernel(const float* __restrict__ x,
                                                            const ushort* __restrict__ wF,
                                                            ushort* __restrict__ hb,
                                                            int M, int T) {
    __shared__ ushort wS[32768];   // 64 KB fragment-major

    const int tid  = threadIdx.x;
    const int wave = tid >> 6;
    const int lane = tid & 63;
    const int quad = lane >> 4;
    const int m16  = lane & 15;

    // stage wF -> LDS: linear coalesced 16B copies, conflict-free
    {
        const uint4* s4 = (const uint4*)wF;
        uint4*       d4 = (uint4*)wS;
        #pragma unroll
        for (int i = 0; i < 16; ++i) d4[tid + i * 256] = s4[tid + i * 256];
    }
    __syncthreads();

    const int gstride = gridDim.x;
    int t = blockIdx.x;
    float4 xv[16];

    // prologue: issue loads for first tile
    {
        int row  = t * 64 + wave * 16 + m16;
        int rowc = row < M ? row : M - 1;
        const float* xr = x + (size_t)rowc * D_FEAT;
        #pragma unroll
        for (int s = 0; s < 8; ++s) {
            const float4* p = (const float4*)(xr + s * 32 + quad * 8);
            xv[2 * s]     = p[0];
            xv[2 * s + 1] = p[1];
        }
    }

    for (; t < T; t += gstride) {
        // convert current tile's loads -> A fragments (waitcnt lands here)
        short8 afrag[8];
        #pragma unroll
        for (int s = 0; s < 8; ++s) {
            float4 lo = xv[2 * s];
            float4 hi = xv[2 * s + 1];
            union { short8 v; ushort u[8]; } af;
            af.u[0] = f2bf(lo.x); af.u[1] = f2bf(lo.y);
            af.u[2] = f2bf(lo.z); af.u[3] = f2bf(lo.w);
            af.u[4] = f2bf(hi.x); af.u[5] = f2bf(hi.y);
            af.u[6] = f2bf(hi.z); af.u[7] = f2bf(hi.w);
            afrag[s] = af.v;
        }

        // issue next tile's loads (overwrite xv; stay in flight across MFMAs)
        int tn = t + gstride;
        if (tn < T) {
            int row  = tn * 64 + wave * 16 + m16;
            int rowc = row < M ? row : M - 1;
            const float* xr = x + (size_t)rowc * D_FEAT;
            #pragma unroll
            for (int s = 0; s < 8; ++s) {
                const float4* p = (const float4*)(xr + s * 32 + quad * 8);
                xv[2 * s]     = p[0];
                xv[2 * s + 1] = p[1];
            }
        }

        // MFMA main loop; B-frags: conflict-free lane-linear ds_read_b128
        floatx4 acc[8] = {};
        #pragma unroll
        for (int s = 0; s < 8; ++s) {
            #pragma unroll
            for (int c = 0; c < 8; ++c) {
                short8 bfrag = *(const short8*)&wS[((s * 8 + c) << 9) + (lane << 3)];
                acc[c] = __builtin_amdgcn_mfma_f32_16x16x32_bf16(afrag[s], bfrag, acc[c], 0, 0, 0);
            }
        }

        // epilogue: D[row=quad*4+i][col=c*16+m16] -> bf16
        #pragma unroll
        for (int c = 0; c < 8; ++c) {
            #pragma unroll
            for (int i = 0; i < 4; ++i) {
                int r = t * 64 + wave * 16 + quad * 4 + i;
                if (r < M) hb[(size_t)r * UNITS + c * 16 + m16] = f2bf(acc[c][i]);
            }
        }
    }
}

// ---------------------------------------------------------------------------
// Coarse scatter: 256 chunks x 1024 threads. Bins of 128 dst nodes -> ~8
// entries (64 B) per (block,bin) run -> near-line-dense staged writes.
// staged entry: {meta = src | (dst&127)<<20, bits(val)}   (unchanged, R7)
// ---------------------------------------------------------------------------
__global__ __launch_bounds__(1024) void coarse_scatter_kernel(const int* __restrict__ src,
                                                              const int* __restrict__ dst,
                                                              const float* __restrict__ vals,
                                                              int* __restrict__ cursor,   // stride 4 ints/bin
                                                              int2* __restrict__ staged,
                                                              int E, int NB, int chunk) {
    __shared__ int s_hist[MAXNB];
    __shared__ int s_base[MAXNB];

    const int tid = threadIdx.x;
    const int T   = 1024;
    const int e0 = blockIdx.x * chunk;
    const int e1 = min(E, e0 + chunk);

    for (int i = tid; i < NB; i += T) s_hist[i] = 0;
    __syncthreads();

    for (int e = e0 + tid; e < e1; e += T)
        atomicAdd(&s_hist[dst[e] >> NBITS], 1);
    __syncthreads();

    for (int b = tid; b < NB; b += T) {
        int c = s_hist[b];
        s_base[b] = (c > 0) ? atomicAdd(&cursor[b * 4], c) : 0;
    }
    __syncthreads();
    for (int i = tid; i < NB; i += T) s_hist[i] = 0;   // reuse as rank counter
    __syncthreads();

    for (int e = e0 + tid; e < e1; e += T) {
        int d = dst[e];
        int b = d >> NBITS;
        int r = s_base[b] + atomicAdd(&s_hist[b], 1);
        if (r < BINCAP) {
            int meta = src[e] | ((d & (BINSZ - 1)) << 20);
            staged[(size_t)b * BINCAP + r] = make_int2(meta, __float_as_int(vals[e]));
        }
    }
}

// ---------------------------------------------------------------------------
// Gather: one block per 128-dst bin. Two-pass counting sort from L2-hot
// staged into sorted LDS, then half-wave per dst, 2x-unrolled dual
// accumulators, one float4 store per row. (unchanged, R7)
// ---------------------------------------------------------------------------
__global__ __launch_bounds__(256) void gather_sort_kernel(const int* __restrict__ cursor,
                                                          const int2* __restrict__ staged,
                                                          const ushort* __restrict__ hb,
                                                          float* __restrict__ out, int N) {
    __shared__ int2 sbuf[BINCAP];
    __shared__ int cnt[BINSZ], ofs[BINSZ], cur[BINSZ];
    __shared__ int gofs[16];

    const int b   = blockIdx.x;
    const int tid = threadIdx.x;

    int n = cursor[b * 4];
    if (n > BINCAP) n = BINCAP;

    for (int i = tid; i < BINSZ; i += 256) cnt[i] = 0;
    __syncthreads();

    const int2* sg = staged + (size_t)b * BINCAP;

    for (int i = tid; i < n; i += 256)
        atomicAdd(&cnt[(sg[i].x >> 20) & (BINSZ - 1)], 1);
    __syncthreads();

    if (tid < 16) {
        int s = 0;
        #pragma unroll
        for (int j = 0; j < 8; ++j) s += cnt[tid * 8 + j];
        gofs[tid] = s;
    }
    __syncthreads();
    if (tid == 0) {
        int run = 0;
        #pragma unroll
        for (int g = 0; g < 16; ++g) { int c = gofs[g]; gofs[g] = run; run += c; }
    }
    __syncthreads();
    if (tid < 16) {
        int run = gofs[tid];
        #pragma unroll
        for (int j = 0; j < 8; ++j) {
            int d = tid * 8 + j;
            int c = cnt[d];
            ofs[d] = run; cur[d] = run; run += c;
        }
    }
    __syncthreads();

    for (int i = tid; i < n; i += 256) {
        int2 e = sg[i];
        int pos = atomicAdd(&cur[(e.x >> 20) & (BINSZ - 1)], 1);
        sbuf[pos] = e;
    }
    __syncthreads();

    const int half = tid >> 5;
    const int lane = tid & 31;

    for (int d0 = 0; d0 < BINSZ; d0 += 8) {
        int d  = d0 + half;
        int dg = b * BINSZ + d;
        if (dg >= N) continue;
        int start = ofs[d];
        int c     = cnt[d];

        float a0 = 0.f, a1 = 0.f, a2 = 0.f, a3 = 0.f;
        float b0 = 0.f, b1 = 0.f, b2 = 0.f, b3 = 0.f;
        int j = 0;
        for (; j + 2 <= c; j += 2) {
            int2 ea = sbuf[start + j];
            int2 eb = sbuf[start + j + 1];
            uint2 ha = *(const uint2*)(hb + (size_t)(ea.x & 0xFFFFF) * UNITS + lane * 4);
            uint2 hc = *(const uint2*)(hb + (size_t)(eb.x & 0xFFFFF) * UNITS + lane * 4);
            float va = __int_as_float(ea.y);
            float vb = __int_as_float(eb.y);
            a0 += va * __uint_as_float(ha.x << 16);
            a1 += va * __uint_as_float(ha.x & 0xFFFF0000u);
            a2 += va * __uint_as_float(ha.y << 16);
            a3 += va * __uint_as_float(ha.y & 0xFFFF0000u);
            b0 += vb * __uint_as_float(hc.x << 16);
            b1 += vb * __uint_as_float(hc.x & 0xFFFF0000u);
            b2 += vb * __uint_as_float(hc.y << 16);
            b3 += vb * __uint_as_float(hc.y & 0xFFFF0000u);
        }
        if (j < c) {
            int2 ea = sbuf[start + j];
            uint2 ha = *(const uint2*)(hb + (size_t)(ea.x & 0xFFFFF) * UNITS + lane * 4);
            float va = __int_as_float(ea.y);
            a0 += va * __uint_as_float(ha.x << 16);
            a1 += va * __uint_as_float(ha.x & 0xFFFF0000u);
            a2 += va * __uint_as_float(ha.y << 16);
            a3 += va * __uint_as_float(ha.y & 0xFFFF0000u);
        }
        float4 r = make_float4(a0 + b0, a1 + b1, a2 + b2, a3 + b3);
        *(float4*)(out + (size_t)dg * UNITS + lane * 4) = r;
    }
}

extern "C" void kernel_launch(void* const* d_in, const int* in_sizes, int n_in,
                              void* d_out, int out_size, void* d_ws, size_t ws_size,
                              hipStream_t stream) {
    const float* x        = (const float*)d_in[0];
    const float* w        = (const float*)d_in[1];
    const int*   adj_src  = (const int*)d_in[2];
    const int*   adj_dst  = (const int*)d_in[3];
    const float* adj_vals = (const float*)d_in[4];
    float*       out      = (float*)d_out;

    const int M = in_sizes[0] / D_FEAT;   // 100000 nodes
    const int E = in_sizes[2];            // 1600000 edges
    const int NB = (M + BINSZ - 1) >> NBITS;   // 782 coarse bins

    // Workspace:
    //   hb:     M*128*2     = 25.6 MB
    //   wF:     128*256*2   = 64 KB (fragment-major)
    //   cursor: NB*4 ints   = 12.5 KB
    //   staged: NB*BINCAP*8 = 15.2 MB
    char*   ws  = (char*)d_ws;
    ushort* hb  = (ushort*)ws;
    size_t  off = (size_t)M * UNITS * sizeof(ushort);
    off = (off + 255) & ~(size_t)255;
    ushort* wF  = (ushort*)(ws + off);
    off += (size_t)128 * 256 * sizeof(ushort);
    int*    cursor = (int*)(ws + off);
    off += (size_t)NB * 4 * sizeof(int);
    off = (off + 15) & ~(size_t)15;
    int2*   staged = (int2*)(ws + off);

    hipMemsetAsync(cursor, 0, (size_t)NB * 4 * sizeof(int), stream);

    wf_prep_kernel<<<128, 256, 0, stream>>>(w, wF);

    const int T = (M + 63) / 64;                  // 1563 row-tiles
    const int grid = (T + 2) / 3;                 // 521 blocks x exactly 3 tiles
    gemm_mfma3_kernel<<<grid, 256, 0, stream>>>(x, wF, hb, M, T);

    const int NSCAT = 256;
    const int chunk = (E + NSCAT - 1) / NSCAT;
    coarse_scatter_kernel<<<NSCAT, 1024, 0, stream>>>(adj_src, adj_dst, adj_vals,
                                                      cursor, staged, E, NB, chunk);

    gather_sort_kernel<<<NB, 256, 0, stream>>>(cursor, staged, hb, out, M);
}